// Round 1
// baseline (278.339 us; speedup 1.0000x reference)
//
#include <hip/hip_runtime.h>
#include <math.h>

#define C_LEN 1024
#define NROW 4096
#define NCHUNK 32
#define CHUNK 32

typedef __attribute__((ext_vector_type(8))) short short8;
typedef __attribute__((ext_vector_type(4))) float f32x4;

__device__ __forceinline__ float siluf(float x) { return x / (1.f + __expf(-x)); }

__device__ __forceinline__ unsigned short f2bf(float f) {
    unsigned u = __builtin_bit_cast(unsigned, f);
    unsigned r = (u + 0x7FFFu + ((u >> 16) & 1u)) >> 16;
    return (unsigned short)r;
}
__device__ __forceinline__ float bf2f(unsigned short v) {
    unsigned u = ((unsigned)v) << 16;
    return __builtin_bit_cast(float, u);
}

// ---------------- prep: weight fp32->bf16 (segs 0..5) + top rmsnorm (seg 6)
// ---------------- + combined-weight pass 1 (seg 7): W_pin = W_{fp,bp} @ W_in, biases
struct WTab {
    const float* s[6];
    unsigned short* d[6];
    int n[6];
};
__global__ __launch_bounds__(256) void k_prep(WTab t, const float* __restrict__ x,
                                              const float* __restrict__ nw,
                                              unsigned short* __restrict__ xn_bf,
                                              const float* __restrict__ W_fp,
                                              const float* __restrict__ W_bp,
                                              const float* __restrict__ W_in,
                                              const float* __restrict__ b_in,
                                              const float* __restrict__ b_fp,
                                              const float* __restrict__ b_bp,
                                              const float* __restrict__ b_wp,
                                              float* __restrict__ Wpin,
                                              float* __restrict__ bmega,
                                              unsigned short* __restrict__ Wmega) {
    int seg = blockIdx.y;
    if (seg < 6) {
        int n = t.n[seg];
        int i = (blockIdx.x * 256 + threadIdx.x) * 4;
        if (i < n) {
            float4 v = *(const float4*)(t.s[seg] + i);
            unsigned short* o = t.d[seg] + i;
            o[0] = f2bf(v.x); o[1] = f2bf(v.y); o[2] = f2bf(v.z); o[3] = f2bf(v.w);
        }
    } else if (seg == 6) {
        int wave = threadIdx.x >> 6, lane = threadIdx.x & 63;
        #pragma unroll
        for (int it = 0; it < 4; ++it) {
            int row = blockIdx.x * 16 + it * 4 + wave;
            if (row < 4096) {
                float2 v = ((const float2*)(x + (size_t)row * 128))[lane];
                float ss = v.x * v.x + v.y * v.y;
                #pragma unroll
                for (int off = 32; off; off >>= 1) ss += __shfl_xor(ss, off, 64);
                float rs = rsqrtf(ss * (1.f / 128.f) + 1e-5f);
                float2 wv = ((const float2*)nw)[lane];
                ushort2 o;
                o.x = f2bf(v.x * rs * wv.x);
                o.y = f2bf(v.y * rs * wv.y);
                ((ushort2*)(xn_bf + (size_t)row * 128))[lane] = o;
            }
        }
    } else {
        int tg = blockIdx.x * 256 + threadIdx.x;
        if (tg < 65536) {
            // W_pin[p][o][i] = sum_j W_{fp,bp}[o,j] * W_in[j,i]   (fp32 + bf16 copy)
            int p = tg >> 15, rem = tg & 32767;
            int o = rem >> 7, i = rem & 127;
            const float* Wsrc = p ? W_bp : W_fp;
            float s = 0.f;
            #pragma unroll 8
            for (int j = 0; j < 256; ++j) s += Wsrc[o * 256 + j] * W_in[j * 128 + i];
            Wpin[p * 32768 + o * 128 + i] = s;
            Wmega[(size_t)(p * 256 + o) * 128 + i] = f2bf(s);
        } else if (tg < 66048) {
            // b_pin[p][o] = W_{fp,bp}[o,:] @ b_in + b_{fp,bp}[o]
            int q = tg - 65536;
            int p = q >> 8, o = q & 255;
            const float* Wsrc = p ? W_bp : W_fp;
            const float* badd = p ? b_bp : b_fp;
            float s = badd[o];
            #pragma unroll 8
            for (int j = 0; j < 256; ++j) s += Wsrc[o * 256 + j] * b_in[j];
            bmega[p * 256 + o] = s;
        } else if (tg < 66304) {
            int q = tg - 66048;
            bmega[512 + q] = b_wp[q];
        }
    }
}

// ---------------- combined-weight pass 2: W_xz = in_w @ W_pin, b_xz = in_w @ b_pin ------
__global__ __launch_bounds__(256) void k_wcomb2(const float* __restrict__ f_in_w,
                                                const float* __restrict__ bk_in_w,
                                                const float* __restrict__ Wpin,
                                                unsigned short* __restrict__ Wmega,
                                                float* __restrict__ bmega) {
    int tg = blockIdx.x * 256 + threadIdx.x;
    if (tg < 262144) {
        int p = tg >> 17, rem = tg & 131071;
        int o = rem >> 7, i = rem & 127;
        const float* inw = p ? bk_in_w : f_in_w;
        const float* wp = Wpin + p * 32768;
        float s = 0.f;
        #pragma unroll 8
        for (int j = 0; j < 256; ++j) s += inw[o * 256 + j] * wp[j * 128 + i];
        Wmega[(size_t)(768 + p * 1024 + o) * 128 + i] = f2bf(s);
    } else if (tg < 264192) {
        int q = tg - 262144;
        int p = q >> 10, o = q & 1023;
        const float* inw = p ? bk_in_w : f_in_w;
        const float* bp = bmega + p * 256;   // b_pin lives in bmega[0:512]
        float s = 0.f;
        #pragma unroll 8
        for (int j = 0; j < 256; ++j) s += inw[o * 256 + j] * bp[j];
        bmega[768 + p * 1024 + o] = s;
    }
}

// ---------------- mega GEMM: [uf | ub | wbuf | xzF | xzB] = xn @ Wmega^T + bmega --------
// M=4096, N=2816, K=128; 128x64 tiles. ub/xzB written at flipped rows.
__global__ __launch_bounds__(256) void k_megagemm(const unsigned short* __restrict__ A,
                                                  const unsigned short* __restrict__ W,
                                                  const float* __restrict__ bias,
                                                  unsigned short* __restrict__ uf,
                                                  unsigned short* __restrict__ ub,
                                                  unsigned short* __restrict__ wbuf,
                                                  unsigned short* __restrict__ xzF,
                                                  unsigned short* __restrict__ xzB) {
    __shared__ __align__(16) unsigned short As[128 * 72];
    __shared__ __align__(16) unsigned short Bs[64 * 72];
    const int K = 128;
    int tid = threadIdx.x;
    int m0 = blockIdx.y * 128, n0 = blockIdx.x * 64;
    int w = tid >> 6, lane = tid & 63;
    int q = lane >> 4, ln = lane & 15;

    unsigned short* Cb; int stride, nc0; bool flip = false, dosilu = false;
    if (n0 < 256)       { Cb = uf;   stride = 256;  nc0 = n0; }
    else if (n0 < 512)  { Cb = ub;   stride = 256;  nc0 = n0 - 256;  flip = true; }
    else if (n0 < 768)  { Cb = wbuf; stride = 256;  nc0 = n0 - 512;  dosilu = true; }
    else if (n0 < 1792) { Cb = xzF;  stride = 1024; nc0 = n0 - 768; }
    else                { Cb = xzB;  stride = 1024; nc0 = n0 - 1792; flip = true; }

    int arow0 = tid >> 1;
    int aseg0 = (tid & 1) * 32;
    int brow = tid >> 2, bseg = (tid & 3) * 16;
    const unsigned short* pa = A + (size_t)(m0 + arow0) * K + aseg0;
    const unsigned short* pw = W + (size_t)(n0 + brow) * K + bseg;

    f32x4 acc[2][4];
    #pragma unroll
    for (int i = 0; i < 2; ++i)
        #pragma unroll
        for (int j = 0; j < 4; ++j) acc[i][j] = (f32x4)(0.f);

    for (int k0 = 0; k0 < K; k0 += 64) {
        #pragma unroll
        for (int h = 0; h < 4; ++h)
            *(short8*)&As[arow0 * 72 + aseg0 + h * 8] = *(const short8*)(pa + h * 8);
        *(short8*)&Bs[brow * 72 + bseg]     = *(const short8*)pw;
        *(short8*)&Bs[brow * 72 + bseg + 8] = *(const short8*)(pw + 8);
        pa += 64; pw += 64;
        __syncthreads();
        short8 a0[2], a1[2];
        #pragma unroll
        for (int i = 0; i < 2; ++i) {
            int row = w * 32 + i * 16 + ln;
            a0[i] = *(const short8*)&As[row * 72 + q * 8];
            a1[i] = *(const short8*)&As[row * 72 + 32 + q * 8];
        }
        #pragma unroll
        for (int j = 0; j < 4; ++j) {
            short8 bf0 = *(const short8*)&Bs[(j * 16 + ln) * 72 + q * 8];
            short8 bf1 = *(const short8*)&Bs[(j * 16 + ln) * 72 + 32 + q * 8];
            #pragma unroll
            for (int i = 0; i < 2; ++i) {
                acc[i][j] = __builtin_amdgcn_mfma_f32_16x16x32_bf16(a0[i], bf0, acc[i][j], 0, 0, 0);
                acc[i][j] = __builtin_amdgcn_mfma_f32_16x16x32_bf16(a1[i], bf1, acc[i][j], 0, 0, 0);
            }
        }
        __syncthreads();
    }
    #pragma unroll
    for (int j = 0; j < 4; ++j) {
        float bsv = bias[n0 + j * 16 + ln];
        int nc = nc0 + j * 16 + ln;
        #pragma unroll
        for (int i = 0; i < 2; ++i) {
            #pragma unroll
            for (int r = 0; r < 4; ++r) {
                int m = m0 + w * 32 + i * 16 + q * 4 + r;
                int mw = flip ? (m ^ (C_LEN - 1)) : m;
                float v = acc[i][j][r] + bsv;
                if (dosilu) v = siluf(v);
                Cb[(size_t)mw * stride + nc] = f2bf(v);
            }
        }
    }
}

// ---------------- 128x64 bf16 GEMM, batched pair (mo stage) ----------------
__global__ __launch_bounds__(256) void k_gemm128(
        const unsigned short* __restrict__ A0, const unsigned short* __restrict__ A1,
        const unsigned short* __restrict__ W0, const unsigned short* __restrict__ W1,
        unsigned short* __restrict__ Cb0, unsigned short* __restrict__ Cb1,
        int N, int K) {
    __shared__ __align__(16) unsigned short As[128 * 72];
    __shared__ __align__(16) unsigned short Bs[64 * 72];
    int p = blockIdx.z;
    const unsigned short* A = p ? A1 : A0;
    const unsigned short* W = p ? W1 : W0;
    unsigned short* Cbf = p ? Cb1 : Cb0;
    int tid = threadIdx.x;
    int m0 = blockIdx.y * 128, n0 = blockIdx.x * 64;
    int w = tid >> 6, lane = tid & 63;
    int q = lane >> 4, ln = lane & 15;

    int arow0 = tid >> 1;
    int aseg0 = (tid & 1) * 32;
    int brow = tid >> 2, bseg = (tid & 3) * 16;
    const unsigned short* pa = A + (size_t)(m0 + arow0) * K + aseg0;
    const unsigned short* pw = W + (size_t)(n0 + brow) * K + bseg;

    f32x4 acc[2][4];
    #pragma unroll
    for (int i = 0; i < 2; ++i)
        #pragma unroll
        for (int j = 0; j < 4; ++j) acc[i][j] = (f32x4)(0.f);

    for (int k0 = 0; k0 < K; k0 += 64) {
        #pragma unroll
        for (int h = 0; h < 4; ++h)
            *(short8*)&As[arow0 * 72 + aseg0 + h * 8] = *(const short8*)(pa + h * 8);
        *(short8*)&Bs[brow * 72 + bseg]     = *(const short8*)pw;
        *(short8*)&Bs[brow * 72 + bseg + 8] = *(const short8*)(pw + 8);
        pa += 64; pw += 64;
        __syncthreads();
        short8 a0[2], a1[2];
        #pragma unroll
        for (int i = 0; i < 2; ++i) {
            int row = w * 32 + i * 16 + ln;
            a0[i] = *(const short8*)&As[row * 72 + q * 8];
            a1[i] = *(const short8*)&As[row * 72 + 32 + q * 8];
        }
        #pragma unroll
        for (int j = 0; j < 4; ++j) {
            short8 bf0 = *(const short8*)&Bs[(j * 16 + ln) * 72 + q * 8];
            short8 bf1 = *(const short8*)&Bs[(j * 16 + ln) * 72 + 32 + q * 8];
            #pragma unroll
            for (int i = 0; i < 2; ++i) {
                acc[i][j] = __builtin_amdgcn_mfma_f32_16x16x32_bf16(a0[i], bf0, acc[i][j], 0, 0, 0);
                acc[i][j] = __builtin_amdgcn_mfma_f32_16x16x32_bf16(a1[i], bf1, acc[i][j], 0, 0, 0);
            }
        }
        __syncthreads();
    }
    #pragma unroll
    for (int i = 0; i < 2; ++i)
        #pragma unroll
        for (int j = 0; j < 4; ++j) {
            int nn = n0 + j * 16 + ln;
            #pragma unroll
            for (int r = 0; r < 4; ++r) {
                int m = m0 + w * 32 + i * 16 + q * 4 + r;
                Cbf[(size_t)m * N + nn] = f2bf(acc[i][j][r]);
            }
        }
}

// ---------------- 64x64 pair GEMM, fp32 out (dbl stage) ----------------
__global__ __launch_bounds__(256) void k_gemm2f(
        const unsigned short* __restrict__ A0, const unsigned short* __restrict__ A1,
        const unsigned short* __restrict__ W0, const unsigned short* __restrict__ W1,
        float* __restrict__ Cf0, float* __restrict__ Cf1,
        int N, int K) {
    __shared__ __align__(16) unsigned short As[64 * 72];
    __shared__ __align__(16) unsigned short Bs[64 * 72];
    int p = blockIdx.z;
    const unsigned short* A = p ? A1 : A0;
    const unsigned short* W = p ? W1 : W0;
    float* Cf = p ? Cf1 : Cf0;
    int tid = threadIdx.x;
    int m0 = blockIdx.y * 64, n0 = blockIdx.x * 64;
    int w = tid >> 6, lane = tid & 63;
    int q = lane >> 4, ln = lane & 15;
    int srow = tid >> 2;
    int sseg = (tid & 3) * 16;

    const unsigned short* pa = A + (size_t)(m0 + srow) * K + sseg;
    int nIdx = n0 + srow;
    const unsigned short* pw = W + (size_t)nIdx * K + sseg;
    bool nOK = (nIdx < N);

    f32x4 acc[4];
    #pragma unroll
    for (int j = 0; j < 4; ++j) acc[j] = (f32x4)(0.f);

    for (int k0 = 0; k0 < K; k0 += 64) {
        *(short8*)&As[srow * 72 + sseg]     = *(const short8*)pa;
        *(short8*)&As[srow * 72 + sseg + 8] = *(const short8*)(pa + 8);
        short8 b0 = (short8)(0), b1 = (short8)(0);
        if (nOK) { b0 = *(const short8*)pw; b1 = *(const short8*)(pw + 8); }
        *(short8*)&Bs[srow * 72 + sseg] = b0;
        *(short8*)&Bs[srow * 72 + sseg + 8] = b1;
        pa += 64; pw += 64;
        __syncthreads();
        short8 af0 = *(const short8*)&As[(w * 16 + ln) * 72 + q * 8];
        short8 af1 = *(const short8*)&As[(w * 16 + ln) * 72 + 32 + q * 8];
        #pragma unroll
        for (int j = 0; j < 4; ++j) {
            short8 bf0 = *(const short8*)&Bs[(j * 16 + ln) * 72 + q * 8];
            short8 bf1 = *(const short8*)&Bs[(j * 16 + ln) * 72 + 32 + q * 8];
            acc[j] = __builtin_amdgcn_mfma_f32_16x16x32_bf16(af0, bf0, acc[j], 0, 0, 0);
            acc[j] = __builtin_amdgcn_mfma_f32_16x16x32_bf16(af1, bf1, acc[j], 0, 0, 0);
        }
        __syncthreads();
    }
    #pragma unroll
    for (int j = 0; j < 4; ++j) {
        int nn = n0 + j * 16 + ln;
        if (nn < N) {
            #pragma unroll
            for (int r = 0; r < 4; ++r) {
                int m = m0 + w * 16 + q * 4 + r;
                Cf[(size_t)m * N + nn] = acc[j][r];
            }
        }
    }
}

// ---------------- final GEMM: out = Acomb @ W_out^T + b_out + x (N=128, K=256) ----------
__global__ __launch_bounds__(256) void k_gemm_out(const unsigned short* __restrict__ A,
                                                  const unsigned short* __restrict__ W,
                                                  const float* __restrict__ bias,
                                                  const float* __restrict__ resid,
                                                  float* __restrict__ Cf) {
    __shared__ __align__(16) unsigned short As[64 * 72];
    __shared__ __align__(16) unsigned short Bs[64 * 72];
    const int N = 128, K = 256;
    int tid = threadIdx.x;
    int m0 = blockIdx.y * 64, n0 = blockIdx.x * 64;
    int w = tid >> 6, lane = tid & 63;
    int q = lane >> 4, ln = lane & 15;
    int srow = tid >> 2;
    int sseg = (tid & 3) * 16;

    const unsigned short* pa = A + (size_t)(m0 + srow) * K + sseg;
    const unsigned short* pw = W + (size_t)(n0 + srow) * K + sseg;

    f32x4 acc[4];
    #pragma unroll
    for (int j = 0; j < 4; ++j) acc[j] = (f32x4)(0.f);

    for (int k0 = 0; k0 < K; k0 += 64) {
        *(short8*)&As[srow * 72 + sseg]     = *(const short8*)pa;
        *(short8*)&As[srow * 72 + sseg + 8] = *(const short8*)(pa + 8);
        *(short8*)&Bs[srow * 72 + sseg]     = *(const short8*)pw;
        *(short8*)&Bs[srow * 72 + sseg + 8] = *(const short8*)(pw + 8);
        pa += 64; pw += 64;
        __syncthreads();
        short8 af0 = *(const short8*)&As[(w * 16 + ln) * 72 + q * 8];
        short8 af1 = *(const short8*)&As[(w * 16 + ln) * 72 + 32 + q * 8];
        #pragma unroll
        for (int j = 0; j < 4; ++j) {
            short8 bf0 = *(const short8*)&Bs[(j * 16 + ln) * 72 + q * 8];
            short8 bf1 = *(const short8*)&Bs[(j * 16 + ln) * 72 + 32 + q * 8];
            acc[j] = __builtin_amdgcn_mfma_f32_16x16x32_bf16(af0, bf0, acc[j], 0, 0, 0);
            acc[j] = __builtin_amdgcn_mfma_f32_16x16x32_bf16(af1, bf1, acc[j], 0, 0, 0);
        }
        __syncthreads();
    }
    #pragma unroll
    for (int j = 0; j < 4; ++j) {
        int nn = n0 + j * 16 + ln;
        float bsv = bias[nn];
        #pragma unroll
        for (int r = 0; r < 4; ++r) {
            int m = m0 + w * 16 + q * 4 + r;
            Cf[(size_t)m * N + nn] = acc[j][r] + bsv + resid[(size_t)m * N + nn];
        }
    }
}

// ---------------- causal depthwise conv (K=4) + silu, both blocks ----------------
__global__ __launch_bounds__(256) void k_conv(const unsigned short* __restrict__ xz0,
                                              const unsigned short* __restrict__ xz1,
                                              const float* __restrict__ cw0,
                                              const float* __restrict__ cw1,
                                              const float* __restrict__ cb0,
                                              const float* __restrict__ cb1,
                                              unsigned short* __restrict__ xc0,
                                              unsigned short* __restrict__ xc1) {
    int pz = blockIdx.z;
    const unsigned short* xz = pz ? xz1 : xz0;
    const float* cw = pz ? cw1 : cw0;
    const float* cb = pz ? cb1 : cb0;
    unsigned short* xconv_bf = pz ? xc1 : xc0;
    int d = blockIdx.x * 256 + threadIdx.x;
    int by = blockIdx.y;
    int b = by >> 6, c0 = (by & 63) * 16;
    float4 cwv = *(const float4*)(cw + d * 4);
    float bias = cb[d];
    const unsigned short* base = xz + (size_t)(b * C_LEN) * 1024 + d;
    float w0 = 0.f, w1 = 0.f, w2 = 0.f;
    if (c0) {
        w0 = bf2f(base[(size_t)(c0 - 3) * 1024]);
        w1 = bf2f(base[(size_t)(c0 - 2) * 1024]);
        w2 = bf2f(base[(size_t)(c0 - 1) * 1024]);
    }
    unsigned short* out = xconv_bf + (size_t)(b * C_LEN + c0) * 512 + d;
    #pragma unroll
    for (int i = 0; i < 16; ++i) {
        float cur = bf2f(base[(size_t)(c0 + i) * 1024]);
        float acc = bias;
        acc = fmaf(cwv.x, w0, acc);
        acc = fmaf(cwv.y, w1, acc);
        acc = fmaf(cwv.z, w2, acc);
        acc = fmaf(cwv.w, cur, acc);
        out[(size_t)i * 512] = f2bf(siluf(acc));
        w0 = w1; w1 = w2; w2 = cur;
    }
}

// ---------------- dt projection -> bf16, 8 rows per thread, both blocks ----------------
__global__ __launch_bounds__(256) void k_dtproj(const float* __restrict__ dbl0,
                                                const float* __restrict__ dbl1,
                                                const float* __restrict__ dtw0,
                                                const float* __restrict__ dtw1,
                                                const float* __restrict__ dtb0,
                                                const float* __restrict__ dtb1,
                                                unsigned short* __restrict__ dt0,
                                                unsigned short* __restrict__ dt1) {
    int pz = blockIdx.z;
    const float* dbl = pz ? dbl1 : dbl0;
    const float* dtw = pz ? dtw1 : dtw0;
    const float* dtb = pz ? dtb1 : dtb0;
    unsigned short* dt = pz ? dt1 : dt0;
    int d = blockIdx.x * 256 + threadIdx.x;
    int r0 = blockIdx.y * 8;
    float4 w0 = *(const float4*)(dtw + d * 16);
    float4 w1 = *(const float4*)(dtw + d * 16 + 4);
    float4 w2 = *(const float4*)(dtw + d * 16 + 8);
    float4 w3 = *(const float4*)(dtw + d * 16 + 12);
    float bias = dtb[d];
    #pragma unroll
    for (int rr = 0; rr < 8; ++rr) {
        int r = r0 + rr;
        const float* row = dbl + (size_t)r * 48;
        float s = bias;
        s = fmaf(row[0], w0.x, s);  s = fmaf(row[1], w0.y, s);
        s = fmaf(row[2], w0.z, s);  s = fmaf(row[3], w0.w, s);
        s = fmaf(row[4], w1.x, s);  s = fmaf(row[5], w1.y, s);
        s = fmaf(row[6], w1.z, s);  s = fmaf(row[7], w1.w, s);
        s = fmaf(row[8], w2.x, s);  s = fmaf(row[9], w2.y, s);
        s = fmaf(row[10], w2.z, s); s = fmaf(row[11], w2.w, s);
        s = fmaf(row[12], w3.x, s); s = fmaf(row[13], w3.y, s);
        s = fmaf(row[14], w3.z, s); s = fmaf(row[15], w3.w, s);
        float sp = fmaxf(s, 0.f) + log1pf(__expf(-fabsf(s)));
        dt[(size_t)r * 512 + d] = f2bf(sp);
    }
}

// ---------------- scan pass 1: local chunk scan (dt bf16) ----------------
__global__ __launch_bounds__(256) void k_scan1(const unsigned short* __restrict__ dt0,
                                               const unsigned short* __restrict__ dt1,
                                               const unsigned short* __restrict__ xc0,
                                               const unsigned short* __restrict__ xc1,
                                               const float* __restrict__ dblA,
                                               const float* __restrict__ dblB,
                                               const float* __restrict__ alog0,
                                               const float* __restrict__ alog1,
                                               float* __restrict__ hfin0,
                                               float* __restrict__ hfin1,
                                               float* __restrict__ Pfin0,
                                               float* __restrict__ Pfin1) {
    int z = blockIdx.z;
    int b = z & 3, p = z >> 2;
    const unsigned short* dt = p ? dt1 : dt0;
    const unsigned short* xconv_bf = p ? xc1 : xc0;
    const float* dbl = p ? dblB : dblA;
    const float* A_log = p ? alog1 : alog0;
    float* hfin = p ? hfin1 : hfin0;
    float* Pfin = p ? Pfin1 : Pfin0;
    int tid = threadIdx.x;
    int nh = tid & 1, dl = tid >> 1;
    int k = blockIdx.x, dg = blockIdx.y;
    int d = dg * 128 + dl;
    float4 al0 = *(const float4*)&A_log[d * 16 + nh * 8];
    float4 al1 = *(const float4*)&A_log[d * 16 + nh * 8 + 4];
    float Ac[8] = {-__expf(al0.x), -__expf(al0.y), -__expf(al0.z), -__expf(al0.w),
                   -__expf(al1.x), -__expf(al1.y), -__expf(al1.z), -__expf(al1.w)};
    size_t r0 = (size_t)(b * C_LEN + k * CHUNK);
    const unsigned short* pdt = dt + r0 * 512 + d;
    const unsigned short* pxv = xconv_bf + r0 * 512 + d;
    const float* pB  = dbl + r0 * 48 + 16 + nh * 8;
    float h[8] = {0.f, 0.f, 0.f, 0.f, 0.f, 0.f, 0.f, 0.f};
    float sdt = 0.f;
    #pragma unroll 8
    for (int c = 0; c < CHUNK; ++c) {
        float dtv = bf2f(*pdt);
        float xv  = bf2f(*pxv);
        float4 B0 = *(const float4*)pB;
        float4 B1 = *(const float4*)(pB + 4);
        float dx = dtv * xv;
        float Bv[8] = {B0.x, B0.y, B0.z, B0.w, B1.x, B1.y, B1.z, B1.w};
        #pragma unroll
        for (int j = 0; j < 8; ++j)
            h[j] = fmaf(__expf(dtv * Ac[j]), h[j], dx * Bv[j]);
        sdt += dtv;
        pdt += 512; pxv += 512; pB += 48;
    }
    size_t idx = ((size_t)(b * NCHUNK + k) * 512 + d) * 16 + nh * 8;
    *(float4*)&hfin[idx]     = make_float4(h[0], h[1], h[2], h[3]);
    *(float4*)&hfin[idx + 4] = make_float4(h[4], h[5], h[6], h[7]);
    *(float4*)&Pfin[idx]     = make_float4(__expf(Ac[0] * sdt), __expf(Ac[1] * sdt),
                                           __expf(Ac[2] * sdt), __expf(Ac[3] * sdt));
    *(float4*)&Pfin[idx + 4] = make_float4(__expf(Ac[4] * sdt), __expf(Ac[5] * sdt),
                                           __expf(Ac[6] * sdt), __expf(Ac[7] * sdt));
}

// ---------------- scan pass 2: sequential carry combine (writes carries into Pfin) -------
__global__ __launch_bounds__(256) void k_scan2(const float* __restrict__ hfin0,
                                               const float* __restrict__ hfin1,
                                               float* __restrict__ Pfin0,
                                               float* __restrict__ Pfin1) {
    int tt = blockIdx.x * 256 + threadIdx.x;   // 0..65535
    int p = tt >> 15;
    int t = tt & 32767;
    const float* hfin = p ? hfin1 : hfin0;
    float* Pfin = p ? Pfin1 : Pfin0;
    int b = t >> 13;
    int dn = t & 8191;
    float carry = 0.f;
    #pragma unroll
    for (int k = 0; k < NCHUNK; ++k) {
        size_t idx = (size_t)(b * NCHUNK + k) * 8192 + dn;
        float pv = Pfin[idx];
        float hf = hfin[idx];
        Pfin[idx] = carry;
        carry = fmaf(pv, carry, hf);
    }
}

// ---------------- scan pass 3: replay with carry-in ----------------
__global__ __launch_bounds__(256) void k_scan3(const unsigned short* __restrict__ dt0,
                                               const unsigned short* __restrict__ dt1,
                                               const unsigned short* __restrict__ xc0,
                                               const unsigned short* __restrict__ xc1,
                                               const float* __restrict__ dblA,
                                               const float* __restrict__ dblB,
                                               const unsigned short* __restrict__ xz0,
                                               const unsigned short* __restrict__ xz1,
                                               const float* __restrict__ alog0,
                                               const float* __restrict__ alog1,
                                               const float* __restrict__ Dp0,
                                               const float* __restrict__ Dp1,
                                               const float* __restrict__ carry0,
                                               const float* __restrict__ carry1,
                                               unsigned short* __restrict__ g0,
                                               unsigned short* __restrict__ g1) {
    int z = blockIdx.z;
    int b = z & 3, p = z >> 2;
    const unsigned short* dt = p ? dt1 : dt0;
    const unsigned short* xconv_bf = p ? xc1 : xc0;
    const float* dbl = p ? dblB : dblA;
    const unsigned short* xz = p ? xz1 : xz0;
    const float* A_log = p ? alog1 : alog0;
    const float* Dp = p ? Dp1 : Dp0;
    const float* carryArr = p ? carry1 : carry0;
    unsigned short* gated_bf = p ? g1 : g0;
    int tid = threadIdx.x;
    int nh = tid & 1, dl = tid >> 1;
    int k = blockIdx.x, dg = blockIdx.y;
    int d = dg * 128 + dl;
    float4 al0 = *(const float4*)&A_log[d * 16 + nh * 8];
    float4 al1 = *(const float4*)&A_log[d * 16 + nh * 8 + 4];
    float Ac[8] = {-__expf(al0.x), -__expf(al0.y), -__expf(al0.z), -__expf(al0.w),
                   -__expf(al1.x), -__expf(al1.y), -__expf(al1.z), -__expf(al1.w)};
    float Dd = Dp[d];
    size_t idx = ((size_t)(b * NCHUNK + k) * 512 + d) * 16 + nh * 8;
    float4 h0 = *(const float4*)&carryArr[idx];
    float4 h1 = *(const float4*)&carryArr[idx + 4];
    float h[8] = {h0.x, h0.y, h0.z, h0.w, h1.x, h1.y, h1.z, h1.w};
    size_t r0 = (size_t)(b * C_LEN + k * CHUNK);
    const unsigned short* pdt = dt + r0 * 512 + d;
    const unsigned short* pxv = xconv_bf + r0 * 512 + d;
    const float* pB  = dbl + r0 * 48 + 16 + nh * 8;
    const float* pC  = dbl + r0 * 48 + 32 + nh * 8;
    const unsigned short* pz = xz + r0 * 1024 + 512 + d;
    unsigned short* pg = gated_bf + r0 * 512 + d;
    #pragma unroll 4
    for (int c = 0; c < CHUNK; ++c) {
        float dtv = bf2f(*pdt);
        float xv  = bf2f(*pxv);
        float4 B0 = *(const float4*)pB;
        float4 B1 = *(const float4*)(pB + 4);
        float4 C0 = *(const float4*)pC;
        float4 C1 = *(const float4*)(pC + 4);
        float dx = dtv * xv;
        float Bv[8] = {B0.x, B0.y, B0.z, B0.w, B1.x, B1.y, B1.z, B1.w};
        float Cv[8] = {C0.x, C0.y, C0.z, C0.w, C1.x, C1.y, C1.z, C1.w};
        float contrib = 0.f;
        #pragma unroll
        for (int j = 0; j < 8; ++j) {
            h[j] = fmaf(__expf(dtv * Ac[j]), h[j], dx * Bv[j]);
            contrib = fmaf(h[j], Cv[j], contrib);
        }
        contrib += __shfl_xor(contrib, 1, 64);
        if (nh == 0) {
            float y = contrib + xv * Dd;
            float zv = bf2f(*pz);
            *pg = f2bf(y * siluf(zv));
        }
        pdt += 512; pxv += 512; pB += 48; pC += 48; pz += 1024; pg += 512;
    }
}

// ---------------- postnorm + comb-A fused: Acomb = wbuf * (mof + flip(mob)) ----------------
__global__ __launch_bounds__(256) void k_postcomb(const unsigned short* __restrict__ mo0,
                                                  const unsigned short* __restrict__ mo1,
                                                  const float* __restrict__ w0,
                                                  const float* __restrict__ w1,
                                                  const unsigned short* __restrict__ uf,
                                                  const unsigned short* __restrict__ ub,
                                                  const unsigned short* __restrict__ wbuf,
                                                  unsigned short* __restrict__ Acomb) {
    __shared__ float red[8];
    int r = blockIdx.x, t = threadIdx.x;
    int rf = r ^ (C_LEN - 1);
    float v0 = bf2f(mo0[(size_t)r * 256 + t]);
    float v1 = bf2f(mo1[(size_t)rf * 256 + t]);
    float ss0 = v0 * v0, ss1 = v1 * v1;
    #pragma unroll
    for (int off = 32; off; off >>= 1) {
        ss0 += __shfl_xor(ss0, off, 64);
        ss1 += __shfl_xor(ss1, off, 64);
    }
    if ((t & 63) == 0) { red[t >> 6] = ss0; red[4 + (t >> 6)] = ss1; }
    __syncthreads();
    float rs0 = rsqrtf((red[0] + red[1] + red[2] + red[3]) * (1.f / 256.f) + 1e-5f);
    float rs1 = rsqrtf((red[4] + red[5] + red[6] + red[7]) * (1.f / 256.f) + 1e-5f);
    float mofv = v0 * rs0 * w0[t] + bf2f(uf[(size_t)r * 256 + t]);
    float mobv = v1 * rs1 * w1[t] + bf2f(ub[(size_t)rf * 256 + t]);
    Acomb[(size_t)r * 256 + t] = f2bf(bf2f(wbuf[(size_t)r * 256 + t]) * (mofv + mobv));
}

extern "C" void kernel_launch(void* const* d_in, const int* in_sizes, int n_in,
                              void* d_out, int out_size, void* d_ws, size_t ws_size,
                              hipStream_t stream) {
    const float* x          = (const float*)d_in[0];
    const float* W_in       = (const float*)d_in[1];
    const float* b_in       = (const float*)d_in[2];
    const float* W_wp       = (const float*)d_in[3];
    const float* b_wp       = (const float*)d_in[4];
    const float* W_fp       = (const float*)d_in[5];
    const float* b_fp       = (const float*)d_in[6];
    const float* W_bp       = (const float*)d_in[7];
    const float* b_bp       = (const float*)d_in[8];
    const float* W_out      = (const float*)d_in[9];
    const float* b_out      = (const float*)d_in[10];
    const float* norm_w_top = (const float*)d_in[11];
    const float* mamba_p[2][10];
    for (int p = 0; p < 2; ++p)
        for (int i = 0; i < 10; ++i)
            mamba_p[p][i] = (const float*)d_in[12 + p * 10 + i];

    // ---- workspace layout ----
    float* ws = (float*)d_ws;
    float* dblP[2]  = {ws + 0,       ws + 196608};
    unsigned short* dtsP[2] = {(unsigned short*)(ws + 393216),
                               (unsigned short*)(ws + 2490368)};
    float* Wpin  = ws + 1441792;   // 65536 fp32 (W_fpin | W_bpin)
    float* bmega = ws + 1507328;   // 2816 fp32
    float* hfinP[2] = {ws + 4587520, ws + 5636096};
    float* PfinP[2] = {ws + 6684672, ws + 7733248};

    unsigned short* us = (unsigned short*)(ws + 8781824);
    unsigned short* xn_bf   = us + 0;
    unsigned short* Acomb   = us + 524288;
    unsigned short* uf_bf   = us + 1572864;
    unsigned short* ub_bf   = us + 2621440;
    unsigned short* wbuf_bf = us + 3670016;
    unsigned short* xzP[2]  = {us + 4718592,  us + 8912896};
    unsigned short* xcP[2]  = {us + 13107200, us + 15204352};
    unsigned short* gP[2]   = {us + 17301504, us + 19398656};
    unsigned short* moP[2]  = {us + 21495808, us + 22544384};
    unsigned short* Wmega   = us + 23592960;  // 2816x128 bf16
    unsigned short* wb      = us + 25690112;
    unsigned short* wb_W_out = wb + 196608;
    unsigned short* wb_xp[2]  = {wb + 491520, wb + 909312};
    unsigned short* wb_outw[2]= {wb + 516096, wb + 933888};

    // 1. prep: straight weight converts + top rmsnorm + combined-weight pass 1
    WTab t;
    t.s[0] = W_wp;            t.d[0] = Wmega + 512 * 128; t.n[0] = 32768;
    t.s[1] = W_out;           t.d[1] = wb_W_out;          t.n[1] = 32768;
    t.s[2] = mamba_p[0][3];   t.d[2] = wb_xp[0];          t.n[2] = 24576;
    t.s[3] = mamba_p[0][8];   t.d[3] = wb_outw[0];        t.n[3] = 131072;
    t.s[4] = mamba_p[1][3];   t.d[4] = wb_xp[1];          t.n[4] = 24576;
    t.s[5] = mamba_p[1][8];   t.d[5] = wb_outw[1];        t.n[5] = 131072;
    k_prep<<<dim3(260, 8), 256, 0, stream>>>(t, x, norm_w_top, xn_bf,
                                             W_fp, W_bp, W_in, b_in, b_fp, b_bp, b_wp,
                                             Wpin, bmega, Wmega);
    // 2. combined-weight pass 2: W_xz = in_w @ W_pin
    k_wcomb2<<<1040, 256, 0, stream>>>(mamba_p[0][0], mamba_p[1][0], Wpin, Wmega, bmega);
    // 3. mega GEMM: uf, ub, wbuf(silu), xzF, xzB   (M=4096, N=2816, K=128)
    k_megagemm<<<dim3(44, 32), 256, 0, stream>>>(xn_bf, Wmega, bmega,
                                                 uf_bf, ub_bf, wbuf_bf, xzP[0], xzP[1]);
    // 4. conv + silu
    k_conv<<<dim3(2, 256, 2), 256, 0, stream>>>(xzP[0], xzP[1],
                                                mamba_p[0][1], mamba_p[1][1],
                                                mamba_p[0][2], mamba_p[1][2],
                                                xcP[0], xcP[1]);
    // 5. dbl = xconv @ xproj_w^T (K=512,N=48) -> fp32
    k_gemm2f<<<dim3(1, 64, 2), 256, 0, stream>>>(xcP[0], xcP[1], wb_xp[0], wb_xp[1],
                                                 dblP[0], dblP[1], 48, 512);
    // 6. dt = softplus(...) -> bf16
    k_dtproj<<<dim3(2, 512, 2), 256, 0, stream>>>(dblP[0], dblP[1],
                                                  mamba_p[0][4], mamba_p[1][4],
                                                  mamba_p[0][5], mamba_p[1][5],
                                                  dtsP[0], dtsP[1]);
    // 7. scan1 (local chunk scans)
    k_scan1<<<dim3(NCHUNK, 4, 8), 256, 0, stream>>>(dtsP[0], dtsP[1], xcP[0], xcP[1],
                                                    dblP[0], dblP[1],
                                                    mamba_p[0][6], mamba_p[1][6],
                                                    hfinP[0], hfinP[1], PfinP[0], PfinP[1]);
    // 8. scan2 (carry combine)
    k_scan2<<<256, 256, 0, stream>>>(hfinP[0], hfinP[1], PfinP[0], PfinP[1]);
    // 9. scan3 (replay with carry-in)
    k_scan3<<<dim3(NCHUNK, 4, 8), 256, 0, stream>>>(dtsP[0], dtsP[1], xcP[0], xcP[1],
                                                    dblP[0], dblP[1], xzP[0], xzP[1],
                                                    mamba_p[0][6], mamba_p[1][6],
                                                    mamba_p[0][7], mamba_p[1][7],
                                                    PfinP[0], PfinP[1], gP[0], gP[1]);
    // 10. mo_raw = gated @ out_w^T (K=512,N=256), 128x64 tiles
    k_gemm128<<<dim3(4, 32, 2), 256, 0, stream>>>(gP[0], gP[1], wb_outw[0], wb_outw[1],
                                                  moP[0], moP[1], 256, 512);
    // 11. postnorm + comb-A fused
    k_postcomb<<<NROW, 256, 0, stream>>>(moP[0], moP[1],
                                         mamba_p[0][9], mamba_p[1][9],
                                         uf_bf, ub_bf, wbuf_bf, Acomb);
    // 12. out = Acomb @ W_out^T + b_out + x
    k_gemm_out<<<dim3(2, 64), 256, 0, stream>>>(Acomb, wb_W_out, b_out, x, (float*)d_out);
}